// Round 13
// baseline (180.248 us; speedup 1.0000x reference)
//
#include <hip/hip_runtime.h>
#include <hip/hip_bf16.h>
#include <stdint.h>

typedef __attribute__((ext_vector_type(8))) short short8;
typedef __attribute__((ext_vector_type(4))) float f32x4;
typedef __attribute__((ext_vector_type(4))) unsigned int uint4v;

#define MFMA16(a, b, c) __builtin_amdgcn_mfma_f32_16x16x32_bf16((a), (b), (c), 0, 0, 0)

// async global->LDS, 16B per lane. LDS dest must be wave-uniform base + lane*16.
#define GLDS16(ldsptr, gptr)                                                                     \
    __builtin_amdgcn_global_load_lds(                                                            \
        (const __attribute__((address_space(1))) unsigned int*)(gptr),                           \
        (__attribute__((address_space(3))) unsigned int*)(ldsptr), 16, 0, 0)

// counted vmcnt wait: never drain to 0 in a main loop (T4)
#define WAITCNT(n) asm volatile("s_waitcnt vmcnt(" #n ")" ::: "memory")

__device__ __forceinline__ unsigned short f2bf(float f) {
    union { float f; unsigned u; } v; v.f = f;
    return (unsigned short)((v.u + 0x7FFFu + ((v.u >> 16) & 1u)) >> 16);
}

// P-fragment redistribution (swapped-QK -> PV A-frag)
__device__ __forceinline__ void kxchg(unsigned& e, unsigned& o) {
    typedef __attribute__((ext_vector_type(2))) unsigned int uint2v;
    uint2v t = __builtin_amdgcn_permlane32_swap(e, o, false, false);
    uint2v f = __builtin_amdgcn_permlane16_swap(t[0], t[1], false, false);
    e = f[0]; o = f[1];
}

__device__ __forceinline__ unsigned cvt_pk_bf16(float lo, float hi) {
    unsigned r;
    asm("v_cvt_pk_bf16_f32 %0, %1, %2" : "=v"(r) : "v"(lo), "v"(hi));
    return r;
}

// ---------------- f32 -> bf16 conversion, all inputs in one launch ----------------
// blocks [0,4096): x (4M elems). blocks [4096,8192): weights, 1024 blocks each.
__global__ void cvt_all(const float* __restrict__ x,
                        const float* __restrict__ wq, const float* __restrict__ wk,
                        const float* __restrict__ wv, const float* __restrict__ wo,
                        unsigned short* __restrict__ xb,
                        unsigned short* __restrict__ wqb, unsigned short* __restrict__ wkb,
                        unsigned short* __restrict__ wvb, unsigned short* __restrict__ wob) {
    int bid = blockIdx.x;
    const float* s; unsigned short* d; int off;
    if (bid < 4096) {
        s = x; d = xb; off = bid;
    } else {
        int w = (bid - 4096) >> 10;
        off = (bid - 4096) & 1023;
        switch (w) {
            case 0: s = wq; d = wqb; break;
            case 1: s = wk; d = wkb; break;
            case 2: s = wv; d = wvb; break;
            default: s = wo; d = wob; break;
        }
    }
    int i = off * 256 + threadIdx.x;
    float4 v = reinterpret_cast<const float4*>(s)[i];
    ushort4 o;
    o.x = f2bf(v.x); o.y = f2bf(v.y); o.z = f2bf(v.z); o.w = f2bf(v.w);
    reinterpret_cast<ushort4*>(d)[i] = o;
}

// ------------- GEMM core: 128x128 tile, BK=64, counted-vmcnt double-buffered pipeline -------
// sl layout: buf b -> As at sl+b*16384, Bs at sl+b*16384+8192 (shorts). 64 KB total.
__device__ __forceinline__ void gemm_core_mfma(
    const unsigned short* __restrict__ A, const unsigned short* __restrict__ W,
    unsigned short* sl, int m0, int n0, f32x4 (&acc)[4][4])
{
    const int tid = threadIdx.x;
    const int lane = tid & 63, wid = tid >> 6;
    const int l15 = lane & 15, grp = lane >> 4;
    const int wm = (wid >> 1) * 64, wn = (wid & 1) * 64;
    const int rs_ = tid >> 3, c8 = tid & 7;

    auto stage = [&](int buf, int kt) {
        unsigned short* As = &sl[buf * 16384];
        unsigned short* Bs = &sl[buf * 16384 + 8192];
#pragma unroll
        for (int q = 0; q < 4; ++q) {
            int r = q * 32 + rs_;
            int sc = (c8 ^ (r & 7)) << 3;
            GLDS16(&As[(q * 256 + tid) * 8], &A[(size_t)(m0 + r) * 1024 + kt + sc]);
        }
#pragma unroll
        for (int q = 0; q < 4; ++q) {
            int r = q * 32 + rs_;
            int sc = (c8 ^ (r & 7)) << 3;
            GLDS16(&Bs[(q * 256 + tid) * 8], &W[(size_t)(n0 + r) * 1024 + kt + sc]);
        }
    };

    stage(0, 0);
    for (int t = 0; t < 16; ++t) {
        if (t < 15) {
            stage((t + 1) & 1, (t + 1) * 64);
            WAITCNT(8);            // tile t's 8 loads done; t+1's 8 stay in flight
        } else {
            WAITCNT(0);
        }
        __builtin_amdgcn_s_barrier();
        const unsigned short* As = &sl[(t & 1) * 16384];
        const unsigned short* Bs = &sl[(t & 1) * 16384 + 8192];
#pragma unroll
        for (int ks = 0; ks < 2; ++ks) {
            short8 a[4], b[4];
#pragma unroll
            for (int i = 0; i < 4; ++i) {
                int row = wm + i * 16 + l15;
                a[i] = *reinterpret_cast<const short8*>(
                    &As[row * 64 + ((ks * 32 + grp * 8) ^ ((row & 7) << 3))]);
            }
#pragma unroll
            for (int j = 0; j < 4; ++j) {
                int row = wn + j * 16 + l15;
                b[j] = *reinterpret_cast<const short8*>(
                    &Bs[row * 64 + ((ks * 32 + grp * 8) ^ ((row & 7) << 3))]);
            }
#pragma unroll
            for (int i = 0; i < 4; ++i)
#pragma unroll
                for (int j = 0; j < 4; ++j)
                    acc[i][j] = MFMA16(a[i], b[j], acc[i][j]);
        }
        if (t < 15) __builtin_amdgcn_s_barrier();   // protect buf reuse by next stage
    }
}

// QKV merged. XCD-chunked swizzle; Q pre-scaled by 0.125*log2(e); V written TRANSPOSED.
__global__ __launch_bounds__(256, 2) void gemm_qkv(
    const unsigned short* __restrict__ A,
    const unsigned short* __restrict__ W0, const unsigned short* __restrict__ W1,
    const unsigned short* __restrict__ W2,
    const float* __restrict__ b0, const float* __restrict__ b1, const float* __restrict__ b2,
    unsigned short* __restrict__ o0, unsigned short* __restrict__ o1,
    unsigned short* __restrict__ vt_out)
{
    __shared__ __attribute__((aligned(16))) unsigned short sl[32768];   // 64 KB

    // bijective XCD swizzle: 768 blocks, XCD k gets logical [96k, 96k+96)
    int id = blockIdx.x + (blockIdx.y << 3) + (blockIdx.z << 8);
    int lg = (id & 7) * 96 + (id >> 3);
    const int bx = lg & 7, by = (lg >> 3) & 31, bz = lg >> 8;

    const unsigned short* W; const float* bias; float oscale;
    if (bz == 0)      { W = W0; bias = b0; oscale = 0.18033688f; }
    else if (bz == 1) { W = W1; bias = b1; oscale = 1.0f; }
    else              { W = W2; bias = b2; oscale = 1.0f; }

    const f32x4 fz = {0.f, 0.f, 0.f, 0.f};
    f32x4 acc[4][4];
#pragma unroll
    for (int i = 0; i < 4; ++i)
#pragma unroll
        for (int j = 0; j < 4; ++j) acc[i][j] = fz;

    const int m0 = by * 128, n0 = bx * 128;
    gemm_core_mfma(A, W, sl, m0, n0, acc);

    const int tid = threadIdx.x, lane = tid & 63, wid = tid >> 6;
    const int l15 = lane & 15, grp = lane >> 4;
    const int wm = (wid >> 1) * 64, wn = (wid & 1) * 64;
    const int bb = m0 >> 11;

    if (bz < 2) {
        unsigned short* out = (bz == 0) ? o0 : o1;
#pragma unroll
        for (int j = 0; j < 4; ++j) {
            int ncol = n0 + wn + j * 16 + l15;
            float bv_ = bias[ncol];
            int h = ncol >> 6, d = ncol & 63;
#pragma unroll
            for (int i = 0; i < 4; ++i)
#pragma unroll
                for (int r = 0; r < 4; ++r) {
                    int mrow = m0 + wm + i * 16 + grp * 4 + r;
                    int ll = mrow & 2047;
                    out[(((size_t)(bb * 16 + h)) * 2048 + ll) * 64 + d] =
                        f2bf((acc[i][j][r] + bv_) * oscale);
                }
        }
    } else {
        // V: transpose through LDS, write VT [bh][64][2048] coalesced
        __syncthreads();                      // core done; reuse sl as ts[128][136]
#pragma unroll
        for (int j = 0; j < 4; ++j) {
            float bv_ = bias[n0 + wn + j * 16 + l15];
#pragma unroll
            for (int i = 0; i < 4; ++i)
#pragma unroll
                for (int r = 0; r < 4; ++r) {
                    int c = wn + j * 16 + l15;            // local d
                    int rr = wm + i * 16 + grp * 4 + r;   // local ll
                    sl[c * 136 + rr] = f2bf(acc[i][j][r] + bv_);
                }
        }
        __syncthreads();
        const int llb = m0 & 2047;
#pragma unroll 4
        for (int it = 0; it < 32; ++it) {
            int c = wid * 32 + it;
            unsigned v = *reinterpret_cast<const unsigned*>(&sl[c * 136 + lane * 2]);
            int ncol = n0 + c;
            size_t row = ((size_t)(bb * 16 + (ncol >> 6))) * 64 + (ncol & 63);
            *reinterpret_cast<unsigned*>(&vt_out[row * 2048 + llb + lane * 2]) = v;
        }
    }
}

// out-projection: f32 output, XCD-chunked swizzle
__global__ __launch_bounds__(256, 2) void gemm_out(
    const unsigned short* __restrict__ A, const unsigned short* __restrict__ W,
    const float* __restrict__ bias, float* __restrict__ out)
{
    __shared__ __attribute__((aligned(16))) unsigned short sl[32768];

    int id = blockIdx.x + (blockIdx.y << 3);
    int lg = (id & 7) * 32 + (id >> 3);
    const int bx = lg & 7, by = lg >> 3;

    const f32x4 fz = {0.f, 0.f, 0.f, 0.f};
    f32x4 acc[4][4];
#pragma unroll
    for (int i = 0; i < 4; ++i)
#pragma unroll
        for (int j = 0; j < 4; ++j) acc[i][j] = fz;

    const int m0 = by * 128, n0 = bx * 128;
    gemm_core_mfma(A, W, sl, m0, n0, acc);

    const int tid = threadIdx.x, lane = tid & 63, wid = tid >> 6;
    const int l15 = lane & 15, grp = lane >> 4;
    const int wm = (wid >> 1) * 64, wn = (wid & 1) * 64;
#pragma unroll
    for (int j = 0; j < 4; ++j) {
        int ncol = n0 + wn + j * 16 + l15;
        float bv_ = bias[ncol];
#pragma unroll
        for (int i = 0; i < 4; ++i)
#pragma unroll
            for (int r = 0; r < 4; ++r) {
                int mrow = m0 + wm + i * 16 + grp * 4 + r;
                out[(size_t)mrow * 1024 + ncol] = acc[i][j][r] + bv_;
            }
    }
}

// --------- Flash attention: swapped QK^T, in-reg P, K via LDS pipeline, V direct from L2 ----
// Delta vs the verified R6/R12 kernel (one lever): V is NOT staged in LDS. Per-XCD V working
// set is 4 bh x 256 KB = 1 MB (L2-resident), and the kernel is LDS-read-throughput-bound
// (16 waves/CU x 16 ds_read_b128 x 12cyc x 32 tiles = 41 us ~= measured 44.5). Reading V
// fragments straight from global halves LDS traffic; the bytes are identical to what the
// swizzled LDS read returned (pre-swizzled source + swizzled read cancel).
// vmcnt safety: K-DMA s(t) is always strictly OLDER than s(t+1), s(t+2) and any compiler-
// issued V loads, so WAITCNT(2/1/0) leaving the 2/1/0 newest ops in flight always completes
// s(t) -- robust to any compiler ordering of its own V loads.
__global__ __launch_bounds__(512, 4) void attn_kernel(
    const unsigned short* __restrict__ Q,
    const unsigned short* __restrict__ Kg,
    const unsigned short* __restrict__ VTg,
    unsigned short* __restrict__ CTX)
{
    __shared__ __attribute__((aligned(16))) unsigned short k_s[4][4096];

    const int tid = threadIdx.x, lane = tid & 63, wid = tid >> 6;
    const int l15 = lane & 15, grp = lane >> 4;

    // bijective XCD swizzle: 512 blocks, XCD k gets bh in [4k, 4k+4) -> K/V L2-resident
    int id = blockIdx.x + (blockIdx.y << 4);
    int lg = ((id & 7) << 6) + (id >> 3);
    const int qt = lg & 15, bh = lg >> 4;

    const int rs_ = tid >> 3, c8 = tid & 7;
    const size_t kvbase = (size_t)bh * 2048 * 64;
    const size_t qbase = kvbase + (size_t)qt * 128 * 64;
    const int scv = (c8 ^ (rs_ & 7)) << 3;

    auto stageK = [&](int t) {
        int b = t & 3;
        GLDS16(&k_s[b][tid * 8], &Kg[kvbase + (size_t)(t * 64 + rs_) * 64 + scv]);
    };

    // prologue: Q direct to registers (issued FIRST so vmcnt counting keeps them oldest),
    // then K tiles 0 and 1.
    short8 aq[2];
    {
        const unsigned short* qp = &Q[qbase + (size_t)(wid * 16 + l15) * 64 + grp * 8];
        aq[0] = *reinterpret_cast<const short8*>(qp);
        aq[1] = *reinterpret_cast<const short8*>(qp + 32);
    }
    stageK(0);
    stageK(1);

    short8 ones;
#pragma unroll
    for (int i = 0; i < 8; ++i) ones[i] = (short)0x3F80;  // bf16 1.0

    // per-lane V fragment base: row d = n*16 + l15 handled per n below; col = ks*32 + grp*8
    const unsigned short* vbase = &VTg[kvbase + (size_t)l15 * 2048 + grp * 8];

    const f32x4 fz = {0.f, 0.f, 0.f, 0.f};
    f32x4 acc[4], acc_l = fz;
#pragma unroll
    for (int n = 0; n < 4; ++n) acc[n] = fz;

#pragma unroll 4
    for (int t = 0; t < 32; ++t) {
        if (t < 30) {
            stageK(t + 2);
            WAITCNT(2);              // K tile t landed; t+1, t+2 in flight
        } else if (t == 30) {
            WAITCNT(1);
        } else {
            WAITCNT(0);
        }
        __builtin_amdgcn_s_barrier();
        const unsigned short* kcur = k_s[t & 3];

        // V fragments for this tile, direct from global (L2-hot). Issued before the QK
        // chain so their latency hides under ds_read + MFMA + exp2.
        short8 bv[2][4];
#pragma unroll
        for (int ks = 0; ks < 2; ++ks)
#pragma unroll
            for (int n = 0; n < 4; ++n)
                bv[ks][n] = *reinterpret_cast<const short8*>(
                    &vbase[(size_t)(n * 16) * 2048 + t * 64 + ks * 32]);

        // S^T = K Q^T (swapped): lane holds S[k = 16j+4grp+r][q = 16wid + l15]
        f32x4 st[4];
#pragma unroll
        for (int j = 0; j < 4; ++j) st[j] = fz;
#pragma unroll
        for (int ks = 0; ks < 2; ++ks)
#pragma unroll
            for (int j = 0; j < 4; ++j) {
                int row = j * 16 + l15;
                short8 bk = *reinterpret_cast<const short8*>(
                    &kcur[row * 64 + ((ks * 32 + grp * 8) ^ ((row & 7) << 3))]);
                st[j] = MFMA16(bk, aq[ks], st[j]);
            }

        // P = exp2(S) in-register; pack to bf16 pairs
        unsigned pk[4][2];
#pragma unroll
        for (int j = 0; j < 4; ++j) {
            float p0 = __builtin_amdgcn_exp2f(st[j][0]);
            float p1 = __builtin_amdgcn_exp2f(st[j][1]);
            float p2 = __builtin_amdgcn_exp2f(st[j][2]);
            float p3 = __builtin_amdgcn_exp2f(st[j][3]);
            pk[j][0] = cvt_pk_bf16(p0, p1);
            pk[j][1] = cvt_pk_bf16(p2, p3);
        }

        // redistribute to PV A-fragments: ap[ks] slot i <- k = 32ks + 8grp + i
        unsigned e0 = pk[0][0], o0 = pk[1][0]; kxchg(e0, o0);
        unsigned e1 = pk[0][1], o1 = pk[1][1]; kxchg(e1, o1);
        unsigned e2 = pk[2][0], o2 = pk[3][0]; kxchg(e2, o2);
        unsigned e3 = pk[2][1], o3 = pk[3][1]; kxchg(e3, o3);
        union { uint4v u; short8 s; } ap0, ap1;
        ap0.u = (uint4v){e0, e1, o0, o1};
        ap1.u = (uint4v){e2, e3, o2, o3};

        // ctx += P @ V; row-sum via ones-MFMA
        __builtin_amdgcn_s_setprio(1);
#pragma unroll
        for (int ks = 0; ks < 2; ++ks) {
            short8 ap = ks ? ap1.s : ap0.s;
            acc_l = MFMA16(ap, ones, acc_l);
#pragma unroll
            for (int n = 0; n < 4; ++n)
                acc[n] = MFMA16(ap, bv[ks][n], acc[n]);
        }
        __builtin_amdgcn_s_setprio(0);
    }

    const int b = bh >> 4, h = bh & 15;
    float inv[4];
#pragma unroll
    for (int r = 0; r < 4; ++r) inv[r] = 1.0f / acc_l[r];
#pragma unroll
    for (int n = 0; n < 4; ++n)
#pragma unroll
        for (int r = 0; r < 4; ++r) {
            int qrow = qt * 128 + wid * 16 + grp * 4 + r;
            CTX[((size_t)(b * 2048 + qrow)) * 1024 + h * 64 + n * 16 + l15] =
                f2bf(acc[n][r] * inv[r]);
        }
}

extern "C" void kernel_launch(void* const* d_in, const int* in_sizes, int n_in,
                              void* d_out, int out_size, void* d_ws, size_t ws_size,
                              hipStream_t stream) {
    const float* x  = (const float*)d_in[0];
    const float* Wq = (const float*)d_in[1];
    const float* bq = (const float*)d_in[2];
    const float* Wk = (const float*)d_in[3];
    const float* bk = (const float*)d_in[4];
    const float* Wv = (const float*)d_in[5];
    const float* bv = (const float*)d_in[6];
    const float* Wo = (const float*)d_in[7];
    const float* bo = (const float*)d_in[8];
    float* out = (float*)d_out;

    char* ws = (char*)d_ws;
    unsigned short* xb  = (unsigned short*)(ws + ((size_t)0));        // 8 MiB [4096][1024]
    unsigned short* wqb = (unsigned short*)(ws + ((size_t)8  << 20)); // 2 MiB each
    unsigned short* wkb = (unsigned short*)(ws + ((size_t)10 << 20));
    unsigned short* wvb = (unsigned short*)(ws + ((size_t)12 << 20));
    unsigned short* wob = (unsigned short*)(ws + ((size_t)14 << 20));
    unsigned short* qb  = (unsigned short*)(ws + ((size_t)16 << 20)); // 8 MiB [32][2048][64]
    unsigned short* kb  = (unsigned short*)(ws + ((size_t)24 << 20));
    unsigned short* vt  = (unsigned short*)(ws + ((size_t)32 << 20)); // 8 MiB [32][64][2048]
    unsigned short* ctx = (unsigned short*)(ws + ((size_t)0));        // reuse xb (done after QKV)

    cvt_all<<<8192, 256, 0, stream>>>(x, Wq, Wk, Wv, Wo, xb, wqb, wkb, wvb, wob);

    gemm_qkv<<<dim3(8, 32, 3), 256, 0, stream>>>(xb, wqb, wkb, wvb, bq, bk, bv, qb, kb, vt);
    attn_kernel<<<dim3(16, 32), 512, 0, stream>>>(qb, kb, vt, ctx);
    gemm_out<<<dim3(8, 32), 256, 0, stream>>>(ctx, wob, bo, out);
}

// Round 14
// 96.755 us; speedup vs baseline: 1.8629x; 1.8629x over previous
//
#include <hip/hip_runtime.h>
#include <hip/hip_bf16.h>
#include <stdint.h>

typedef __attribute__((ext_vector_type(8))) short short8;
typedef __attribute__((ext_vector_type(4))) float f32x4;
typedef __attribute__((ext_vector_type(16))) float f32x16;
typedef __attribute__((ext_vector_type(4))) unsigned int uint4v;
typedef __attribute__((ext_vector_type(2))) unsigned int uint2v;

#define MFMA16(a, b, c) __builtin_amdgcn_mfma_f32_16x16x32_bf16((a), (b), (c), 0, 0, 0)
#define MFMA32(a, b, c) __builtin_amdgcn_mfma_f32_32x32x16_bf16((a), (b), (c), 0, 0, 0)

// async global->LDS, 16B per lane. LDS dest must be wave-uniform base + lane*16.
#define GLDS16(ldsptr, gptr)                                                                     \
    __builtin_amdgcn_global_load_lds(                                                            \
        (const __attribute__((address_space(1))) unsigned int*)(gptr),                           \
        (__attribute__((address_space(3))) unsigned int*)(ldsptr), 16, 0, 0)

// counted vmcnt wait: never drain to 0 in a main loop (T4)
#define WAITCNT(n) asm volatile("s_waitcnt vmcnt(" #n ")" ::: "memory")

__device__ __forceinline__ unsigned short f2bf(float f) {
    union { float f; unsigned u; } v; v.f = f;
    return (unsigned short)((v.u + 0x7FFFu + ((v.u >> 16) & 1u)) >> 16);
}

__device__ __forceinline__ unsigned cvt_pk_bf16(float lo, float hi) {
    unsigned r;
    asm("v_cvt_pk_bf16_f32 %0, %1, %2" : "=v"(r) : "v"(lo), "v"(hi));
    return r;
}

// ---------------- f32 -> bf16 conversion, all inputs in one launch ----------------
__global__ void cvt_all(const float* __restrict__ x,
                        const float* __restrict__ wq, const float* __restrict__ wk,
                        const float* __restrict__ wv, const float* __restrict__ wo,
                        unsigned short* __restrict__ xb,
                        unsigned short* __restrict__ wqb, unsigned short* __restrict__ wkb,
                        unsigned short* __restrict__ wvb, unsigned short* __restrict__ wob) {
    int bid = blockIdx.x;
    const float* s; unsigned short* d; int off;
    if (bid < 4096) {
        s = x; d = xb; off = bid;
    } else {
        int w = (bid - 4096) >> 10;
        off = (bid - 4096) & 1023;
        switch (w) {
            case 0: s = wq; d = wqb; break;
            case 1: s = wk; d = wkb; break;
            case 2: s = wv; d = wvb; break;
            default: s = wo; d = wob; break;
        }
    }
    int i = off * 256 + threadIdx.x;
    float4 v = reinterpret_cast<const float4*>(s)[i];
    ushort4 o;
    o.x = f2bf(v.x); o.y = f2bf(v.y); o.z = f2bf(v.z); o.w = f2bf(v.w);
    reinterpret_cast<ushort4*>(d)[i] = o;
}

// ------------- GEMM core: 128x128 tile, BK=64, counted-vmcnt double-buffered pipeline -------
__device__ __forceinline__ void gemm_core_mfma(
    const unsigned short* __restrict__ A, const unsigned short* __restrict__ W,
    unsigned short* sl, int m0, int n0, f32x4 (&acc)[4][4])
{
    const int tid = threadIdx.x;
    const int lane = tid & 63, wid = tid >> 6;
    const int l15 = lane & 15, grp = lane >> 4;
    const int wm = (wid >> 1) * 64, wn = (wid & 1) * 64;
    const int rs_ = tid >> 3, c8 = tid & 7;

    auto stage = [&](int buf, int kt) {
        unsigned short* As = &sl[buf * 16384];
        unsigned short* Bs = &sl[buf * 16384 + 8192];
#pragma unroll
        for (int q = 0; q < 4; ++q) {
            int r = q * 32 + rs_;
            int sc = (c8 ^ (r & 7)) << 3;
            GLDS16(&As[(q * 256 + tid) * 8], &A[(size_t)(m0 + r) * 1024 + kt + sc]);
        }
#pragma unroll
        for (int q = 0; q < 4; ++q) {
            int r = q * 32 + rs_;
            int sc = (c8 ^ (r & 7)) << 3;
            GLDS16(&Bs[(q * 256 + tid) * 8], &W[(size_t)(n0 + r) * 1024 + kt + sc]);
        }
    };

    stage(0, 0);
    for (int t = 0; t < 16; ++t) {
        if (t < 15) {
            stage((t + 1) & 1, (t + 1) * 64);
            WAITCNT(8);            // tile t's 8 loads done; t+1's 8 stay in flight
        } else {
            WAITCNT(0);
        }
        __builtin_amdgcn_s_barrier();
        const unsigned short* As = &sl[(t & 1) * 16384];
        const unsigned short* Bs = &sl[(t & 1) * 16384 + 8192];
#pragma unroll
        for (int ks = 0; ks < 2; ++ks) {
            short8 a[4], b[4];
#pragma unroll
            for (int i = 0; i < 4; ++i) {
                int row = wm + i * 16 + l15;
                a[i] = *reinterpret_cast<const short8*>(
                    &As[row * 64 + ((ks * 32 + grp * 8) ^ ((row & 7) << 3))]);
            }
#pragma unroll
            for (int j = 0; j < 4; ++j) {
                int row = wn + j * 16 + l15;
                b[j] = *reinterpret_cast<const short8*>(
                    &Bs[row * 64 + ((ks * 32 + grp * 8) ^ ((row & 7) << 3))]);
            }
#pragma unroll
            for (int i = 0; i < 4; ++i)
#pragma unroll
                for (int j = 0; j < 4; ++j)
                    acc[i][j] = MFMA16(a[i], b[j], acc[i][j]);
        }
        if (t < 15) __builtin_amdgcn_s_barrier();   // protect buf reuse by next stage
    }
}

// QKV merged. XCD-chunked swizzle; Q pre-scaled by 0.125*log2(e); V written TRANSPOSED.
__global__ __launch_bounds__(256, 2) void gemm_qkv(
    const unsigned short* __restrict__ A,
    const unsigned short* __restrict__ W0, const unsigned short* __restrict__ W1,
    const unsigned short* __restrict__ W2,
    const float* __restrict__ b0, const float* __restrict__ b1, const float* __restrict__ b2,
    unsigned short* __restrict__ o0, unsigned short* __restrict__ o1,
    unsigned short* __restrict__ vt_out)
{
    __shared__ __attribute__((aligned(16))) unsigned short sl[32768];   // 64 KB

    int id = blockIdx.x + (blockIdx.y << 3) + (blockIdx.z << 8);
    int lg = (id & 7) * 96 + (id >> 3);
    const int bx = lg & 7, by = (lg >> 3) & 31, bz = lg >> 8;

    const unsigned short* W; const float* bias; float oscale;
    if (bz == 0)      { W = W0; bias = b0; oscale = 0.18033688f; }
    else if (bz == 1) { W = W1; bias = b1; oscale = 1.0f; }
    else              { W = W2; bias = b2; oscale = 1.0f; }

    const f32x4 fz = {0.f, 0.f, 0.f, 0.f};
    f32x4 acc[4][4];
#pragma unroll
    for (int i = 0; i < 4; ++i)
#pragma unroll
        for (int j = 0; j < 4; ++j) acc[i][j] = fz;

    const int m0 = by * 128, n0 = bx * 128;
    gemm_core_mfma(A, W, sl, m0, n0, acc);

    const int tid = threadIdx.x, lane = tid & 63, wid = tid >> 6;
    const int l15 = lane & 15, grp = lane >> 4;
    const int wm = (wid >> 1) * 64, wn = (wid & 1) * 64;
    const int bb = m0 >> 11;

    if (bz < 2) {
        unsigned short* out = (bz == 0) ? o0 : o1;
#pragma unroll
        for (int j = 0; j < 4; ++j) {
            int ncol = n0 + wn + j * 16 + l15;
            float bv_ = bias[ncol];
            int h = ncol >> 6, d = ncol & 63;
#pragma unroll
            for (int i = 0; i < 4; ++i)
#pragma unroll
                for (int r = 0; r < 4; ++r) {
                    int mrow = m0 + wm + i * 16 + grp * 4 + r;
                    int ll = mrow & 2047;
                    out[(((size_t)(bb * 16 + h)) * 2048 + ll) * 64 + d] =
                        f2bf((acc[i][j][r] + bv_) * oscale);
                }
        }
    } else {
        // V: transpose through LDS, write VT [bh][64][2048] coalesced
        __syncthreads();
#pragma unroll
        for (int j = 0; j < 4; ++j) {
            float bv_ = bias[n0 + wn + j * 16 + l15];
#pragma unroll
            for (int i = 0; i < 4; ++i)
#pragma unroll
                for (int r = 0; r < 4; ++r) {
                    int c = wn + j * 16 + l15;            // local d
                    int rr = wm + i * 16 + grp * 4 + r;   // local ll
                    sl[c * 136 + rr] = f2bf(acc[i][j][r] + bv_);
                }
        }
        __syncthreads();
        const int llb = m0 & 2047;
#pragma unroll 4
        for (int it = 0; it < 32; ++it) {
            int c = wid * 32 + it;
            unsigned v = *reinterpret_cast<const unsigned*>(&sl[c * 136 + lane * 2]);
            int ncol = n0 + c;
            size_t row = ((size_t)(bb * 16 + (ncol >> 6))) * 64 + (ncol & 63);
            *reinterpret_cast<unsigned*>(&vt_out[row * 2048 + llb + lane * 2]) = v;
        }
    }
}

// out-projection: f32 output, XCD-chunked swizzle
__global__ __launch_bounds__(256, 2) void gemm_out(
    const unsigned short* __restrict__ A, const unsigned short* __restrict__ W,
    const float* __restrict__ bias, float* __restrict__ out)
{
    __shared__ __attribute__((aligned(16))) unsigned short sl[32768];

    int id = blockIdx.x + (blockIdx.y << 3);
    int lg = (id & 7) * 32 + (id >> 3);
    const int bx = lg & 7, by = lg >> 3;

    const f32x4 fz = {0.f, 0.f, 0.f, 0.f};
    f32x4 acc[4][4];
#pragma unroll
    for (int i = 0; i < 4; ++i)
#pragma unroll
        for (int j = 0; j < 4; ++j) acc[i][j] = fz;

    const int m0 = by * 128, n0 = bx * 128;
    gemm_core_mfma(A, W, sl, m0, n0, acc);

    const int tid = threadIdx.x, lane = tid & 63, wid = tid >> 6;
    const int l15 = lane & 15, grp = lane >> 4;
    const int wm = (wid >> 1) * 64, wn = (wid & 1) * 64;
#pragma unroll
    for (int j = 0; j < 4; ++j) {
        int ncol = n0 + wn + j * 16 + l15;
        float bv_ = bias[ncol];
#pragma unroll
        for (int i = 0; i < 4; ++i)
#pragma unroll
            for (int r = 0; r < 4; ++r) {
                int mrow = m0 + wm + i * 16 + grp * 4 + r;
                out[(size_t)mrow * 1024 + ncol] = acc[i][j][r] + bv_;
            }
    }
}

// --------- Flash attention: 32x32x16 MFMA, 8 waves x 32 q (QBLK=256), R6 staging ------------
// Staging/sync BYTE-IDENTICAL to the verified R6/R12 kernel (512 thr, 2 GLDS16/thr, 4 bufs,
// stage(t+2)->WAITCNT(4/2/0)->s_barrier, unroll 4). Compute uses the 32x32x16 shape so one
// wave's full K/V tile read feeds 32 q (halves LDS-read traffic/q, the measured bound).
// Layouts: C/D col=lane&31,row=(reg&3)+8*(reg>>2)+4*(lane>>5) [m74/m101 verified]; A/B
// row/col=lane%32, k=(lane/32)*8+i (same pattern as the proven 16x16 GEMM operands).
// P redistribution: pk[kb][g][p]=cvt_pk(st[4g+2p],st[4g+2p+1]); (x',y')=permlane32_swap
// (pk[kb][2j][p], pk[kb][2j+1][p]); A(2kb+j)={x'(0),x'(1),y'(0),y'(1)}. Only the in-system-
// validated swap32 primitive; derivation in session notes.
__global__ __launch_bounds__(512, 2) void attn_kernel(
    const unsigned short* __restrict__ Q,
    const unsigned short* __restrict__ Kg,
    const unsigned short* __restrict__ VTg,
    unsigned short* __restrict__ CTX)
{
    __shared__ __attribute__((aligned(16))) unsigned short k_s[4][4096];
    __shared__ __attribute__((aligned(16))) unsigned short vt_s[4][4096];

    const int tid = threadIdx.x, lane = tid & 63, wid = tid >> 6;  // wid 0..7
    const int l31 = lane & 31, h = lane >> 5;

    // bijective XCD swizzle: 256 blocks, XCD k gets bh in [4k, 4k+4)
    int id = blockIdx.x + (blockIdx.y << 3);
    int lg = ((id & 7) << 5) + (id >> 3);
    const int qt = lg & 7, bh = lg >> 3;

    const int rs_ = tid >> 3, c8 = tid & 7;
    const size_t kvbase = (size_t)bh * 2048 * 64;
    const size_t qbase = kvbase + (size_t)qt * 256 * 64;
    const int scv = (c8 ^ (rs_ & 7)) << 3;

    auto stageKV = [&](int t) {
        int b = t & 3;
        GLDS16(&k_s[b][tid * 8], &Kg[kvbase + (size_t)(t * 64 + rs_) * 64 + scv]);
        GLDS16(&vt_s[b][tid * 8], &VTg[kvbase + (size_t)rs_ * 2048 + t * 64 + scv]);
    };

    // prologue: Q direct to registers (issued FIRST so vmcnt counting keeps them oldest).
    // B-frag: col q = wid*32 + l31, k(hd) = kq*16 + h*8 + i  -> 16B contiguous per lane.
    short8 aq[4];
    {
        const unsigned short* qp = &Q[qbase + (size_t)(wid * 32 + l31) * 64 + h * 8];
#pragma unroll
        for (int kq = 0; kq < 4; ++kq)
            aq[kq] = *reinterpret_cast<const short8*>(qp + kq * 16);
    }
    stageKV(0);
    stageKV(1);

    short8 ones;
#pragma unroll
    for (int i = 0; i < 8; ++i) ones[i] = (short)0x3F80;  // bf16 1.0

    f32x16 acc[2], acc_l;
#pragma unroll
    for (int i = 0; i < 16; ++i) { acc[0][i] = 0.f; acc[1][i] = 0.f; acc_l[i] = 0.f; }

#pragma unroll 4
    for (int t = 0; t < 32; ++t) {
        if (t < 30) {
            stageKV(t + 2);
            WAITCNT(4);              // tile t landed; t+1, t+2 in flight
        } else if (t == 30) {
            WAITCNT(2);
        } else {
            WAITCNT(0);
        }
        __builtin_amdgcn_s_barrier();
        const unsigned short* kcur = k_s[t & 3];
        const unsigned short* vcur = vt_s[t & 3];

        // S^T = K Q^T (swapped, 32x32x16): st[kb] lane(l31=q? no: col=q=l31 via B, A rows=k)
        // lane l, reg r: q = l31, k = kb*32 + (r&3)+8*(r>>2)+4*h
        f32x16 st[2];
#pragma unroll
        for (int i = 0; i < 16; ++i) { st[0][i] = 0.f; st[1][i] = 0.f; }
#pragma unroll
        for (int kb = 0; kb < 2; ++kb)
#pragma unroll
            for (int kq = 0; kq < 4; ++kq) {
                int row = kb * 32 + l31;
                short8 ak = *reinterpret_cast<const short8*>(
                    &kcur[row * 64 + ((kq * 16 + h * 8) ^ ((row & 7) << 3))]);
                st[kb] = MFMA32(ak, aq[kq], st[kb]);
            }

        // P = exp2(S) in-register; pack adjacent-k pairs: pk[kb][g][p] <- regs 4g+2p, 4g+2p+1
        unsigned pk[2][4][2];
#pragma unroll
        for (int kb = 0; kb < 2; ++kb)
#pragma unroll
            for (int g = 0; g < 4; ++g)
#pragma unroll
                for (int p = 0; p < 2; ++p)
                    pk[kb][g][p] = cvt_pk_bf16(
                        __builtin_amdgcn_exp2f(st[kb][4 * g + 2 * p]),
                        __builtin_amdgcn_exp2f(st[kb][4 * g + 2 * p + 1]));

        // PV A-frags: A(kk=2kb+j).word[w]: w=p from h'=0 lane, w=p+2 from h'=1 lane, of
        // group gg=2j+h  ->  (x',y') = swap32(pk[kb][2j][p], pk[kb][2j+1][p]).
        union { uint4v u; short8 s; } ap[4];
#pragma unroll
        for (int kb = 0; kb < 2; ++kb)
#pragma unroll
            for (int j = 0; j < 2; ++j) {
                uint2v s0 = __builtin_amdgcn_permlane32_swap(
                    pk[kb][2 * j][0], pk[kb][2 * j + 1][0], false, false);
                uint2v s1 = __builtin_amdgcn_permlane32_swap(
                    pk[kb][2 * j][1], pk[kb][2 * j + 1][1], false, false);
                ap[2 * kb + j].u = (uint4v){s0[0], s1[0], s0[1], s1[1]};
            }

        // ctx += P @ V (A=P rows q, B=V cols d, k=16 per MFMA); row-sum via ones-MFMA
        __builtin_amdgcn_s_setprio(1);
#pragma unroll
        for (int kk = 0; kk < 4; ++kk) {
            acc_l = MFMA32(ap[kk].s, ones, acc_l);
#pragma unroll
            for (int db = 0; db < 2; ++db) {
                int row = db * 32 + l31;
                short8 bv = *reinterpret_cast<const short8*>(
                    &vcur[row * 64 + ((kk * 16 + h * 8) ^ ((row & 7) << 3))]);
                acc[db] = MFMA32(ap[kk].s, bv, acc[db]);
            }
        }
        __builtin_amdgcn_s_setprio(0);
    }

    // epilogue: lane l, reg r: q_local = (r&3)+8*(r>>2)+4*h, d = db*32 + l31
    const int b = bh >> 4, hh = bh & 15;
#pragma unroll
    for (int r = 0; r < 16; ++r) {
        int q_local = (r & 3) + 8 * (r >> 2) + 4 * h;
        int qrow = qt * 256 + wid * 32 + q_local;
        float inv = 1.0f / acc_l[r];
#pragma unroll
        for (int db = 0; db < 2; ++db)
            CTX[((size_t)(b * 2048 + qrow)) * 1024 + hh * 64 + db * 32 + l31] =
                f2bf(acc[db][r] * inv);
    }
}

extern "C" void kernel_launch(void* const* d_in, const int* in_sizes, int n_in,
                              void* d_out, int out_size, void* d_ws, size_t ws_size,
                              hipStream_t stream) {
    const float* x  = (const float*)d_in[0];
    const float* Wq = (const float*)d_in[1];
    const float* bq = (const float*)d_in[2];
    const float* Wk = (const float*)d_in[3];
    const float* bk = (const float*)d_in[4];
    const float* Wv = (const float*)d_in[5];
    const float* bv = (const float*)d_in[6];
    const float* Wo = (const float*)d_in[7];
    const float* bo = (const float*)d_in[8];
    float* out = (float*)d_out;

    char* ws = (char*)d_ws;
    unsigned short* xb  = (unsigned short*)(ws + ((size_t)0));        // 8 MiB [4096][1024]
    unsigned short* wqb = (unsigned short*)(ws + ((size_t)8  << 20)); // 2 MiB each
    unsigned short* wkb = (unsigned short*)(ws + ((size_t)10 << 20));
    unsigned short* wvb = (unsigned short*)(ws + ((size_t)12 << 20));
    unsigned short* wob = (unsigned short*)(ws + ((size_t)14 << 20));
    unsigned short* qb  = (unsigned short*)(ws + ((size_t)16 << 20)); // 8 MiB [32][2048][64]
    unsigned short* kb  = (unsigned short*)(ws + ((size_t)24 << 20));
    unsigned short* vt  = (unsigned short*)(ws + ((size_t)32 << 20)); // 8 MiB [32][64][2048]
    unsigned short* ctx = (unsigned short*)(ws + ((size_t)0));        // reuse xb (done after QKV)

    cvt_all<<<8192, 256, 0, stream>>>(x, Wq, Wk, Wv, Wo, xb, wqb, wkb, wvb, wob);

    gemm_qkv<<<dim3(8, 32, 3), 256, 0, stream>>>(xb, wqb, wkb, wvb, bq, bk, bv, qb, kb, vt);
    attn_kernel<<<dim3(8, 32), 512, 0, stream>>>(qb, kb, vt, ctx);
    gemm_out<<<dim3(8, 32), 256, 0, stream>>>(ctx, wob, bo, out);
}